// Round 6
// baseline (7470.983 us; speedup 1.0000x reference)
//
#include <hip/hip_runtime.h>

typedef unsigned short u16;
typedef unsigned int u32;
typedef unsigned long long u64;
typedef __attribute__((ext_vector_type(8))) short short8;
typedef __attribute__((ext_vector_type(4))) float f4;
typedef __attribute__((ext_vector_type(2))) float fvec2;
typedef __attribute__((ext_vector_type(4))) unsigned short us4;
typedef __attribute__((ext_vector_type(4))) u32 v4u;

#define MFMA_BF16(a, b, c) __builtin_amdgcn_mfma_f32_16x16x32_bf16((a), (b), (c), 0, 0, 0)

#define Bsz 64
#define Ssz 1024
#define Isz 512
#define Hsz 512
#define G4  2048
#define SCH 128
#define NCHUNK 8
#define SCAN_NB 64

// ---- workspace layout (bytes). xc is BF16 (33,554,432 B per chunk):
// XC0 [8388608, 41943040), XC1 [41943040, 75497472). Total 72 MB.
// (R4/R5 bug: xc was fp32 = 67 MB/chunk, so XC0/XC1 overlapped by 32 MB and
// the fused GEMM corrupted the xc being scanned -> deterministic absmax ~1.)
#define WS_DONE  0          // 1024*4 consumed-step counters
#define WS_BIAS  4096       // 2048*4
#define WS_CBUF  12288      // 64*512*4
#define WS_HBUF  262144     // u32[4][64][512] tagged h ring (512 KB)
#define WS_WI    786432     // 2048*512*2
#define WS_WH    2883584    // 2048*512*2
#define WS_XC0   8388608    // u16[64][128][2048]
#define WS_XC1   41943040   // u16[64][128][2048]

#define HF_OFF ((size_t)Bsz * Ssz * Hsz)
#define CF_OFF (HF_OFF + (size_t)Bsz * Hsz)

__device__ __forceinline__ u16 bf16rne(float f) {
    u32 x = __float_as_uint(f);
    return (u16)((x + 0x7fffu + ((x >> 16) & 1u)) >> 16);
}
__device__ __forceinline__ float bf2f(u16 h) {
    return __uint_as_float(((u32)h) << 16);
}
__device__ __forceinline__ float sigf(float x) { return 1.0f / (1.0f + __expf(-x)); }
__device__ __forceinline__ float tanh_(float x) { return 1.0f - 2.0f / (__expf(2.0f * x) + 1.0f); }

// ------------------------------------------------------------------
// prep
// ------------------------------------------------------------------
struct PrepArgs {
    const float* h0; const float* c0;
    const float* wi[4]; const float* wh[4];
    const float* bi[4]; const float* bh[4];
    u16* Wi; u16* Wh; float* bias; u32* hbuf; float* cbuf; int* done;
};
// segment ends
#define PE_WI   1048576
#define PE_WH   2097152
#define PE_B    2099200
#define PE_C    2131968
#define PE_H    2263040
#define PE_D    2264064

__global__ void lstm_prep(PrepArgs a) {
    long i = (long)blockIdx.x * 256 + threadIdx.x;
    if (i < PE_WI) {
        int rowp = (int)(i >> 9), k = (int)(i & 511);
        a.Wi[i] = bf16rne(a.wi[rowp & 3][(rowp >> 2) * Isz + k]);
    } else if (i < PE_WH) {
        long j = i - PE_WI;
        int rowp = (int)(j >> 9), k = (int)(j & 511);
        a.Wh[j] = bf16rne(a.wh[rowp & 3][(rowp >> 2) * Hsz + k]);
    } else if (i < PE_B) {
        int j = (int)(i - PE_WH);
        a.bias[j] = a.bi[j & 3][j >> 2] + a.bh[j & 3][j >> 2];
    } else if (i < PE_C) {
        int j = (int)(i - PE_B);
        a.cbuf[j] = a.c0[j];
    } else if (i < PE_H) {
        int j = (int)(i - PE_C);           // 0..131071 over 4 slots
        int slot = j >> 15, idx = j & 32767;
        // slot 3 = "step -1" (tag 0xFFFF) holds h0; others poisoned 0xFFFE
        a.hbuf[j] = (slot == 3) ? (0xFFFF0000u | (u32)bf16rne(a.h0[idx]))
                                : 0xFFFE0000u;
    } else if (i < PE_D) {
        a.done[i - PE_H] = 0;
    }
}

// ------------------------------------------------------------------
// x_proj GEMM body (bf16 output). 128(s) x 128(n) tile per block.
// ------------------------------------------------------------------
__device__ __forceinline__ void gemm_body(
    const float* __restrict__ inp, const u16* __restrict__ Wi,
    u16* __restrict__ xc, int t0, int gb, char* smem)
{
    u16* Al = (u16*)smem;            // 128*40
    u16* Bl = (u16*)smem + 128 * 40; // 128*40
    const int tid = threadIdx.x;
    const int L = tid & 63, w = tid >> 6;
    const int q = L >> 4, lm = L & 15;
    const int nt = gb & 15, b = gb >> 4;
    const float* Abase = inp + ((size_t)b * Ssz + t0) * Isz;
    const u16* Bbase = Wi + (size_t)nt * 128 * Isz;
    const int mh = (w & 1) * 64, nh = (w >> 1) * 64;

    f4 acc[4][4];
#pragma unroll
    for (int i = 0; i < 4; ++i)
#pragma unroll
        for (int j = 0; j < 4; ++j) acc[i][j] = (f4){0.f, 0.f, 0.f, 0.f};

    for (int kt = 0; kt < 16; ++kt) {
        const int k0 = kt * 32;
#pragma unroll
        for (int r = 0; r < 4; ++r) {
            int flat = tid + r * 256;
            int m = flat >> 3, kq = flat & 7;
            f4 v = *(const f4*)(Abase + (size_t)m * Isz + k0 + kq * 4);
            us4 h = {bf16rne(v.x), bf16rne(v.y), bf16rne(v.z), bf16rne(v.w)};
            *(us4*)(&Al[m * 40 + kq * 4]) = h;
        }
#pragma unroll
        for (int r = 0; r < 2; ++r) {
            int flat = tid + r * 256;
            int n = flat >> 2, kq = flat & 3;
            *(short8*)(&Bl[n * 40 + kq * 8]) =
                *(const short8*)(Bbase + (size_t)n * Isz + k0 + kq * 8);
        }
        __syncthreads();
        short8 af[4], bfr[4];
#pragma unroll
        for (int i = 0; i < 4; ++i)
            af[i] = *(const short8*)(&Al[(mh + i * 16 + lm) * 40 + q * 8]);
#pragma unroll
        for (int j = 0; j < 4; ++j)
            bfr[j] = *(const short8*)(&Bl[(nh + j * 16 + lm) * 40 + q * 8]);
#pragma unroll
        for (int i = 0; i < 4; ++i)
#pragma unroll
            for (int j = 0; j < 4; ++j)
                acc[i][j] = MFMA_BF16(af[i], bfr[j], acc[i][j]);
        __syncthreads();
    }
    u16* Obase = xc + (size_t)b * SCH * G4 + (size_t)nt * 128;
#pragma unroll
    for (int i = 0; i < 4; ++i)
#pragma unroll
        for (int j = 0; j < 4; ++j)
#pragma unroll
            for (int r = 0; r < 4; ++r) {
                int m = mh + i * 16 + q * 4 + r;
                int n = nh + j * 16 + lm;
                Obase[(size_t)m * G4 + n] = bf16rne(acc[i][j][r]);
            }
}

__global__ __launch_bounds__(256) void xproj_gemm(
    const float* __restrict__ inp, const u16* __restrict__ Wi,
    u16* __restrict__ xc, int t0)
{
    __shared__ __align__(16) char smem[20480];
    gemm_body(inp, Wi, xc, t0, blockIdx.x, smem);
}

// ------------------------------------------------------------------
// Dependence-carrying wait: the "+v" constraints force every consumer of
// the 16 gather registers to be scheduled AFTER this s_waitcnt.
// ------------------------------------------------------------------
#define WAITR(R)                                                          \
    asm volatile("s_waitcnt vmcnt(0)"                                     \
        : "+v"(R[0][0]), "+v"(R[0][1]), "+v"(R[1][0]), "+v"(R[1][1]),     \
          "+v"(R[2][0]), "+v"(R[2][1]), "+v"(R[3][0]), "+v"(R[3][1]),     \
          "+v"(R[4][0]), "+v"(R[4][1]), "+v"(R[5][0]), "+v"(R[5][1]),     \
          "+v"(R[6][0]), "+v"(R[6][1]), "+v"(R[7][0]), "+v"(R[7][1])      \
        :: "memory")

// ------------------------------------------------------------------
// tag-verify + repack: 8 tagged u32 -> short8 bf16 fragment.
// Each u32 word carries {tag:16, bf16:16} -> self-validating; retry
// (coherent reload) until all 8 tags match texp.
// ------------------------------------------------------------------
__device__ __forceinline__ short8 vrp(v4u r0, v4u r1, const u32* p, u32 texp) {
    while (1) {
        u32 bad = ((r0.x ^ texp) | (r0.y ^ texp) | (r0.z ^ texp) | (r0.w ^ texp) |
                   (r1.x ^ texp) | (r1.y ^ texp) | (r1.z ^ texp) | (r1.w ^ texp))
                  & 0xffff0000u;
        if (!bad) break;
        asm volatile("s_sleep 1\n\t"
                     "global_load_dwordx4 %0, %2, off sc0 sc1\n\t"
                     "global_load_dwordx4 %1, %3, off sc0 sc1\n\t"
                     "s_waitcnt vmcnt(0)"
                     : "=&v"(r0), "=&v"(r1)
                     : "v"(p), "v"(p + 4)
                     : "memory");
    }
    v4u pk;
    pk.x = __builtin_amdgcn_perm(r0.y, r0.x, 0x05040100u);
    pk.y = __builtin_amdgcn_perm(r0.w, r0.z, 0x05040100u);
    pk.z = __builtin_amdgcn_perm(r1.y, r1.x, 0x05040100u);
    pk.w = __builtin_amdgcn_perm(r1.w, r1.z, 0x05040100u);
    union { v4u u; short8 s; } c; c.u = pk;
    return c.s;
}

// ------------------------------------------------------------------
// scan body (blocks 0..63 of the fused kernel)
// ------------------------------------------------------------------
__device__ void scan_body(
    const u16* __restrict__ xc, const u16* __restrict__ Whp,
    const float* __restrict__ bias, u32* __restrict__ hbuf,
    float* __restrict__ cbuf, int* __restrict__ done,
    float* __restrict__ out, int t0, char* smem)
{
    float* gate_buf = (float*)smem;   // 64*32 floats
    const int tid = threadIdx.x, bid = blockIdx.x;
    const int L = tid & 63, w = tid >> 6;
    const int q = L >> 4, lm = L & 15;
    const int row0 = bid * 32;
    const int j0 = bid * 8;
    const int myb = w * 16 + lm;

    short8 wb[16][2];
#pragma unroll
    for (int kt = 0; kt < 16; ++kt)
#pragma unroll
        for (int jt = 0; jt < 2; ++jt) {
            int n = row0 + jt * 16 + lm;
            wb[kt][jt] = *(const short8*)(Whp + (size_t)n * Hsz + kt * 32 + q * 8);
        }

    const int be = tid >> 2;
    const int u0 = (tid & 3) * 2;
    const f4 bias0 = *(const f4*)(bias + row0 + u0 * 4);
    const f4 bias1 = *(const f4*)(bias + row0 + u0 * 4 + 4);
    float c0r = cbuf[be * Hsz + j0 + u0];
    float c1r = cbuf[be * Hsz + j0 + u0 + 1];

    for (int t = t0; t < t0 + SCH; ++t) {
        const int sl = t - t0;
        // x prefetch (bf16 -> fp32), independent of h
        const u16* xrow = xc + ((size_t)be * SCH + sl) * G4 + row0 + u0 * 4;
        short8 xr = *(const short8*)xrow;
        f4 xv0 = (f4){bf2f((u16)xr[0]), bf2f((u16)xr[1]),
                      bf2f((u16)xr[2]), bf2f((u16)xr[3])};
        f4 xv1 = (f4){bf2f((u16)xr[4]), bf2f((u16)xr[5]),
                      bf2f((u16)xr[6]), bf2f((u16)xr[7])};

        const u32* hb = hbuf + (size_t)((t - 1) & 3) * 32768 + (size_t)myb * 512;
        const u32 texp = (u32)((t - 1) & 0xffff) << 16;

        v4u r[8][2];
        short8 af[16];

        // ---- half 1: issue kt 0..7 (coherent, coalescing 16B loads) ----
#pragma unroll
        for (int kt = 0; kt < 8; ++kt) {
            const u32* p = hb + kt * 32 + q * 8;
            asm volatile("global_load_dwordx4 %0, %1, off sc0 sc1"
                         : "=v"(r[kt][0]) : "v"(p) : "memory");
            asm volatile("global_load_dwordx4 %0, %1, off sc0 sc1"
                         : "=v"(r[kt][1]) : "v"(p + 4) : "memory");
        }
        // writer-throttle check, overlapped with gather latency.
        // h(t) overwrites slot t&3, i.e. h(t-4), consumed at step t-3;
        // the publish below is barrier-ordered after this poll.
        if (tid == 0 && t >= 3) {
            while (__hip_atomic_load(&done[t - 3], __ATOMIC_RELAXED,
                                     __HIP_MEMORY_SCOPE_AGENT) < SCAN_NB)
                __builtin_amdgcn_s_sleep(1);
        }
        WAITR(r);
#pragma unroll
        for (int kt = 0; kt < 8; ++kt)
            af[kt] = vrp(r[kt][0], r[kt][1], hb + kt * 32 + q * 8, texp);

        // ---- issue half 2, then MFMA half 1 under it ----
#pragma unroll
        for (int kt = 8; kt < 16; ++kt) {
            const u32* p = hb + kt * 32 + q * 8;
            asm volatile("global_load_dwordx4 %0, %1, off sc0 sc1"
                         : "=v"(r[kt - 8][0]) : "v"(p) : "memory");
            asm volatile("global_load_dwordx4 %0, %1, off sc0 sc1"
                         : "=v"(r[kt - 8][1]) : "v"(p + 4) : "memory");
        }
        f4 acc0 = (f4){0.f, 0.f, 0.f, 0.f}, acc1 = acc0;
#pragma unroll
        for (int kt = 0; kt < 8; ++kt) {
            acc0 = MFMA_BF16(af[kt], wb[kt][0], acc0);
            acc1 = MFMA_BF16(af[kt], wb[kt][1], acc1);
        }
        WAITR(r);
#pragma unroll
        for (int kt = 8; kt < 16; ++kt)
            af[kt] = vrp(r[kt - 8][0], r[kt - 8][1], hb + kt * 32 + q * 8, texp);
#pragma unroll
        for (int kt = 8; kt < 16; ++kt) {
            acc0 = MFMA_BF16(af[kt], wb[kt][0], acc0);
            acc1 = MFMA_BF16(af[kt], wb[kt][1], acc1);
        }

#pragma unroll
        for (int r2 = 0; r2 < 4; ++r2) {
            int brow = w * 16 + q * 4 + r2;
            gate_buf[brow * 32 + lm] = acc0[r2];
            gate_buf[brow * 32 + 16 + lm] = acc1[r2];
        }
        __syncthreads();
        if (tid == 0)   // this block finished reading slot (t-1)&3
            __hip_atomic_fetch_add(&done[t], 1, __ATOMIC_RELAXED,
                                   __HIP_MEMORY_SCOPE_AGENT);

        f4 g0 = *(const f4*)(&gate_buf[be * 32 + u0 * 4]);
        f4 g1 = *(const f4*)(&gate_buf[be * 32 + u0 * 4 + 4]);
        g0 += xv0 + bias0;
        g1 += xv1 + bias1;
        float i1 = sigf(g0.x), ff1 = sigf(g0.y), gg1 = tanh_(g0.z), o1 = sigf(g0.w);
        c0r = ff1 * c0r + i1 * gg1;
        float h1 = o1 * tanh_(c0r);
        float i2 = sigf(g1.x), ff2 = sigf(g1.y), gg2 = tanh_(g1.z), o2 = sigf(g1.w);
        c1r = ff2 * c1r + i2 * gg2;
        float h2 = o2 * tanh_(c1r);

        // publish tagged h(t): single 8B write-through store; data IS the flag
        u32 tagw = (u32)(t & 0xffff) << 16;
        u64 wv = (u64)(tagw | (u32)bf16rne(h1)) |
                 ((u64)(tagw | (u32)bf16rne(h2)) << 32);
        u64* hw = (u64*)(hbuf + (size_t)(t & 3) * 32768 + be * 512 + j0 + u0);
        __hip_atomic_store(hw, wv, __ATOMIC_RELAXED, __HIP_MEMORY_SCOPE_AGENT);

        *(fvec2*)(out + ((size_t)be * Ssz + t) * Hsz + j0 + u0) = (fvec2){h1, h2};
        if (t == Ssz - 1) {
            out[HF_OFF + be * Hsz + j0 + u0] = h1;
            out[HF_OFF + be * Hsz + j0 + u0 + 1] = h2;
            out[CF_OFF + be * Hsz + j0 + u0] = c0r;
            out[CF_OFF + be * Hsz + j0 + u0 + 1] = c1r;
        }
        __syncthreads();   // protect gate_buf reads from next iteration's writes
    }
    cbuf[be * Hsz + j0 + u0] = c0r;
    cbuf[be * Hsz + j0 + u0 + 1] = c1r;
}

// ------------------------------------------------------------------
// fused: blocks 0..63 scan chunk t0; blocks 64..1087 x_proj for t0+SCH
// ------------------------------------------------------------------
__global__ __launch_bounds__(256, 1) void lstm_fused(
    const u16* __restrict__ xcr, u16* __restrict__ xcw,
    const float* __restrict__ inp, const u16* __restrict__ Wi,
    const u16* __restrict__ Whp, const float* __restrict__ bias,
    u32* __restrict__ hbuf, float* __restrict__ cbuf, int* __restrict__ done,
    float* __restrict__ out, int t0, int do_gemm)
{
    __shared__ __align__(16) char smem[20480];
    if (blockIdx.x < SCAN_NB) {
        scan_body(xcr, Whp, bias, hbuf, cbuf, done, out, t0, smem);
    } else if (do_gemm) {
        gemm_body(inp, Wi, xcw, t0 + SCH, blockIdx.x - SCAN_NB, smem);
    }
}

// ------------------------------------------------------------------
extern "C" void kernel_launch(void* const* d_in, const int* in_sizes, int n_in,
                              void* d_out, int out_size, void* d_ws, size_t ws_size,
                              hipStream_t stream) {
    const float* inputs = (const float*)d_in[0];
    char* W = (char*)d_ws;
    int*   done = (int*)(W + WS_DONE);
    float* bias = (float*)(W + WS_BIAS);
    float* cbuf = (float*)(W + WS_CBUF);
    u32*   hbuf = (u32*)(W + WS_HBUF);
    u16*   Wi   = (u16*)(W + WS_WI);
    u16*   Wh   = (u16*)(W + WS_WH);
    u16*   xc[2] = { (u16*)(W + WS_XC0), (u16*)(W + WS_XC1) };

    PrepArgs a;
    a.h0 = (const float*)d_in[1];
    a.c0 = (const float*)d_in[2];
    for (int g = 0; g < 4; ++g) {
        a.wi[g] = (const float*)d_in[3 + g];
        a.wh[g] = (const float*)d_in[7 + g];
        a.bi[g] = (const float*)d_in[11 + g];
    }
    // tail dict order is b_hi, b_hf, b_ho, b_hg -> remap to (i,f,g,o)
    a.bh[0] = (const float*)d_in[15];
    a.bh[1] = (const float*)d_in[16];
    a.bh[2] = (const float*)d_in[18];
    a.bh[3] = (const float*)d_in[17];
    a.Wi = Wi; a.Wh = Wh; a.bias = bias; a.hbuf = hbuf; a.cbuf = cbuf; a.done = done;

    lstm_prep<<<(PE_D + 255) / 256, 256, 0, stream>>>(a);

    float* out = (float*)d_out;
    xproj_gemm<<<dim3(1024), 256, 0, stream>>>(inputs, Wi, xc[0], 0);
    for (int c = 0; c < NCHUNK; ++c) {
        lstm_fused<<<dim3(SCAN_NB + 1024), 256, 0, stream>>>(
            xc[c & 1], xc[(c + 1) & 1], inputs, Wi, Wh, bias,
            hbuf, cbuf, done, out, c * SCH, c < NCHUNK - 1 ? 1 : 0);
    }
}